// Round 1
// baseline (1215.666 us; speedup 1.0000x reference)
//
#include <hip/hip_runtime.h>
#include <cstdint>
#include <cstddef>

#define BB 4
#define SS 2048
#define HIDD 512
#define HH 8
#define DHH 64
#define DBB 8

typedef __attribute__((ext_vector_type(4))) float f32x4;
typedef __attribute__((ext_vector_type(8))) short s16x8;
typedef __attribute__((ext_vector_type(4))) short s16x4;

__device__ __forceinline__ short f2bf(float x) {
  unsigned u = __builtin_bit_cast(unsigned, x);
  u += 0x7FFFu + ((u >> 16) & 1u);
  return (short)(u >> 16);
}
__device__ __forceinline__ float bf2f(short s) {
  unsigned u = ((unsigned)(unsigned short)s) << 16;
  return __builtin_bit_cast(float, u);
}

// C[m][n] = sum_k X[m][k] * W[n][k] + bias[n]   (X: [8192,512] fp32, W: [512,512] fp32)
// MODE 0: out bf16 qh layout [B,H,S,D], value *= 0.125 (softmax scale folded)
// MODE 1: out bf16 kh layout [B,H,S,D]
// MODE 2: out bf16 vh layout [B,H,D,S] (pre-transposed for PV B-operand)
// MODE 3: out fp32 [8192,512]
template <int MODE>
__global__ __launch_bounds__(256) void gemm_xwT(const float* __restrict__ X,
                                                const float* __restrict__ W,
                                                const float* __restrict__ bias,
                                                float* __restrict__ outF,
                                                short* __restrict__ outB) {
  __shared__ short xs[64][40];   // 40-short rows: 20-bank pattern, conflict-free b128
  __shared__ short wsh[64][40];
  const int tid = threadIdx.x;
  const int wave = tid >> 6, lane = tid & 63;
  const int quad = lane >> 4, m16 = lane & 15;
  const int m0 = blockIdx.x * 64, n0 = blockIdx.y * 64;
  const int wm = (wave & 1) * 32, wn = (wave >> 1) * 32;

  f32x4 acc[2][2];
#pragma unroll
  for (int a = 0; a < 2; a++)
#pragma unroll
    for (int b2 = 0; b2 < 2; b2++) acc[a][b2] = (f32x4){0.f, 0.f, 0.f, 0.f};

  for (int k0 = 0; k0 < HIDD; k0 += 32) {
#pragma unroll
    for (int i = 0; i < 2; i++) {
      int c = tid + i * 256;
      int row = c >> 3, kc = c & 7;
      f32x4 xv = *(const f32x4*)(X + (size_t)(m0 + row) * HIDD + k0 + kc * 4);
      f32x4 wv = *(const f32x4*)(W + (size_t)(n0 + row) * HIDD + k0 + kc * 4);
      s16x4 xb, wb2;
#pragma unroll
      for (int j = 0; j < 4; j++) { xb[j] = f2bf(xv[j]); wb2[j] = f2bf(wv[j]); }
      *(s16x4*)(&xs[row][kc * 4]) = xb;
      *(s16x4*)(&wsh[row][kc * 4]) = wb2;
    }
    __syncthreads();
    s16x8 af[2], bfr[2];
    af[0] = *(const s16x8*)(&xs[wm + m16][quad * 8]);
    af[1] = *(const s16x8*)(&xs[wm + 16 + m16][quad * 8]);
    bfr[0] = *(const s16x8*)(&wsh[wn + m16][quad * 8]);
    bfr[1] = *(const s16x8*)(&wsh[wn + 16 + m16][quad * 8]);
    acc[0][0] = __builtin_amdgcn_mfma_f32_16x16x32_bf16(af[0], bfr[0], acc[0][0], 0, 0, 0);
    acc[0][1] = __builtin_amdgcn_mfma_f32_16x16x32_bf16(af[0], bfr[1], acc[0][1], 0, 0, 0);
    acc[1][0] = __builtin_amdgcn_mfma_f32_16x16x32_bf16(af[1], bfr[0], acc[1][0], 0, 0, 0);
    acc[1][1] = __builtin_amdgcn_mfma_f32_16x16x32_bf16(af[1], bfr[1], acc[1][1], 0, 0, 0);
    __syncthreads();
  }

#pragma unroll
  for (int a = 0; a < 2; a++)
#pragma unroll
    for (int b2 = 0; b2 < 2; b2++)
#pragma unroll
      for (int r = 0; r < 4; r++) {
        int m = m0 + wm + a * 16 + quad * 4 + r;   // C row = quad*4+reg (verified layout)
        int n = n0 + wn + b2 * 16 + m16;           // C col = lane&15
        float val = acc[a][b2][r] + bias[n];
        if (MODE == 0) {
          int b_ = m >> 11, s = m & 2047, h = n >> 6, d = n & 63;
          outB[((size_t)(b_ * HH + h) * SS + s) * DHH + d] = f2bf(val * 0.125f);
        } else if (MODE == 1) {
          int b_ = m >> 11, s = m & 2047, h = n >> 6, d = n & 63;
          outB[((size_t)(b_ * HH + h) * SS + s) * DHH + d] = f2bf(val);
        } else if (MODE == 2) {
          int b_ = m >> 11, s = m & 2047, h = n >> 6, d = n & 63;
          outB[((size_t)(b_ * HH + h) * DHH + d) * SS + s] = f2bf(val);
        } else {
          outF[(size_t)m * HIDD + n] = val;
        }
      }
}

// Flash attention, bias fused. One block = (b, 16 q rows, ALL 8 heads); wave w = head w.
// attn_bias is read exactly once across the whole grid (register-prefetched one tile ahead).
// K/V fragments are read DIRECTLY from global (kh/vh are 8.4 MB each -> L2/L3-resident;
// LDS staging of them was pure overhead + the dominant bank-conflict source).
// Single barrier per iteration via double-buffered projected-bias tile bp[2].
__global__ __launch_bounds__(512, 8) void flash_attn(const short* __restrict__ qh,
                                                     const short* __restrict__ kh,
                                                     const short* __restrict__ vh,
                                                     const float* __restrict__ attn_bias,
                                                     const float* __restrict__ Wb,
                                                     const float* __restrict__ bb,
                                                     float* __restrict__ attn_out) {
  __shared__ short bp[2][HH][16][34];  // projected bias, bf16, double-buffered
  __shared__ short pbuf[HH][16][40];   // per-wave P tile, A-layout staging

  const int tid = threadIdx.x;
  const int wave = tid >> 6, lane = tid & 63;
  const int quad = lane >> 4, m16 = lane & 15;
  // XCD-bijective remap (512 wg = 8 XCD * 64): each XCD works one batch's contiguous q-range
  const int wg = (int)blockIdx.x;
  const int lb = ((wg & 7) << 6) | (wg >> 3);
  const int b = lb >> 7;
  const int q0 = (lb & 127) << 4;
  const int h = wave;

  // Q A-fragments (A[m=lane&15][k=quad*8+j]), already *0.125 from projection
  const size_t qoff = ((size_t)((b * HH + h) * SS) + q0 + m16) * DHH;
  s16x8 qf0 = *(const s16x8*)(qh + qoff + quad * 8);
  s16x8 qf1 = *(const s16x8*)(qh + qoff + 32 + quad * 8);

  // direct-global fragment bases (per-lane)
  const short* kbase = kh + ((size_t)(b * HH + h) * SS + m16) * DHH + quad * 8;      // + (k0+nt*16)*64
  const short* vbase = vh + ((size_t)((b * HH + h) * DHH) + m16) * SS + quad * 8;    // + dt*16*2048 + k0

  const int ql = tid >> 5, kl = tid & 31;  // 512 threads = 16x32 (q,k) pairs
  const float* bptr = attn_bias + ((size_t)(b * SS + q0 + ql) * SS + kl) * DBB;

  f32x4 oacc[4];
#pragma unroll
  for (int dt = 0; dt < 4; dt++) oacc[dt] = (f32x4){0.f, 0.f, 0.f, 0.f};
  float m_r[4], l_r[4];
#pragma unroll
  for (int r = 0; r < 4; r++) { m_r[r] = -3.0e38f; l_r[r] = 0.f; }

  // prologue: project bias tile 0 into bp[0]  (Wb/bb read as uniform scalar loads)
  {
    f32x4 c0 = *(const f32x4*)(bptr);
    f32x4 c1 = *(const f32x4*)(bptr + 4);
#pragma unroll
    for (int h2 = 0; h2 < 8; h2++) {
      float a2 = bb[h2];
#pragma unroll
      for (int d = 0; d < 4; d++) {
        a2 += c0[d] * Wb[h2 * 8 + d];
        a2 += c1[d] * Wb[h2 * 8 + 4 + d];
      }
      bp[0][h2][ql][kl] = f2bf(a2);
    }
  }
  __syncthreads();  // bp[0] ready

  for (int it = 0; it < 64; ++it) {
    const int k0 = it << 5;
    const int cur = it & 1;

    // prefetch next bias tile into registers (the only HBM stream) — consumed at iter end
    f32x4 n0, n1;
    if (it < 63) {
      const float* np = bptr + (size_t)(k0 + 32) * DBB;
      n0 = *(const f32x4*)(np);
      n1 = *(const f32x4*)(np + 4);
    }

    // ---- QK^T: 16q x 32k, K B-fragments direct from global (L2-resident) ----
    f32x4 sc[2];
#pragma unroll
    for (int nt = 0; nt < 2; nt++) {
      const short* kp = kbase + (size_t)(k0 + nt * 16) * DHH;
      s16x8 kf0 = *(const s16x8*)(kp);
      s16x8 kf1 = *(const s16x8*)(kp + 32);
      f32x4 z = (f32x4){0.f, 0.f, 0.f, 0.f};
      z = __builtin_amdgcn_mfma_f32_16x16x32_bf16(qf0, kf0, z, 0, 0, 0);
      z = __builtin_amdgcn_mfma_f32_16x16x32_bf16(qf1, kf1, z, 0, 0, 0);
      sc[nt] = z;
    }

    // ---- online softmax (C layout: row = quad*4+r, col = m16) ----
#pragma unroll
    for (int r = 0; r < 4; r++) {
      int row = quad * 4 + r;
      float s0 = sc[0][r] + bf2f(bp[cur][h][row][m16]);
      float s1 = sc[1][r] + bf2f(bp[cur][h][row][16 + m16]);
      float v = fmaxf(s0, s1);
      v = fmaxf(v, __shfl_xor(v, 1, 16));
      v = fmaxf(v, __shfl_xor(v, 2, 16));
      v = fmaxf(v, __shfl_xor(v, 4, 16));
      v = fmaxf(v, __shfl_xor(v, 8, 16));
      float nm = fmaxf(m_r[r], v);
      float al = __expf(m_r[r] - nm);
      m_r[r] = nm;
      float p0 = __expf(s0 - nm);
      float p1 = __expf(s1 - nm);
      float rs = p0 + p1;
      rs += __shfl_xor(rs, 1, 16);
      rs += __shfl_xor(rs, 2, 16);
      rs += __shfl_xor(rs, 4, 16);
      rs += __shfl_xor(rs, 8, 16);
      l_r[r] = l_r[r] * al + rs;
#pragma unroll
      for (int dt = 0; dt < 4; dt++) oacc[dt][r] *= al;
      pbuf[wave][row][m16] = f2bf(p0);
      pbuf[wave][row][16 + m16] = f2bf(p1);
    }

    // ---- PV: O += P(16x32) @ V(32x64), V B-fragments direct from global ----
    s16x8 pf = *(const s16x8*)(&pbuf[wave][m16][quad * 8]);
#pragma unroll
    for (int dt = 0; dt < 4; dt++) {
      const short* vp = vbase + (size_t)(dt * 16) * SS + k0;
      s16x8 vf = *(const s16x8*)(vp);
      oacc[dt] = __builtin_amdgcn_mfma_f32_16x16x32_bf16(pf, vf, oacc[dt], 0, 0, 0);
    }

    // ---- project prefetched bias tile it+1 into bp[cur^1] ----
    if (it < 63) {
#pragma unroll
      for (int h2 = 0; h2 < 8; h2++) {
        float a2 = bb[h2];
#pragma unroll
        for (int d = 0; d < 4; d++) {
          a2 += n0[d] * Wb[h2 * 8 + d];
          a2 += n1[d] * Wb[h2 * 8 + 4 + d];
        }
        bp[cur ^ 1][h2][ql][kl] = f2bf(a2);
      }
    }
    __syncthreads();  // bp[cur^1] ready; all reads of bp[cur] done
  }

  // epilogue: attn_out[b, s, h*64+d] fp32
#pragma unroll
  for (int dt = 0; dt < 4; dt++)
#pragma unroll
    for (int r = 0; r < 4; r++) {
      float val = oacc[dt][r] / l_r[r];
      attn_out[(size_t)(b * SS + q0 + quad * 4 + r) * HIDD + h * 64 + dt * 16 + m16] = val;
    }
}

extern "C" void kernel_launch(void* const* d_in, const int* in_sizes, int n_in,
                              void* d_out, int out_size, void* d_ws, size_t ws_size,
                              hipStream_t stream) {
  const float* q = (const float*)d_in[0];
  const float* k = (const float*)d_in[1];
  const float* v = (const float*)d_in[2];
  const float* attn_bias = (const float*)d_in[3];
  const float* Wq = (const float*)d_in[4];
  const float* bq = (const float*)d_in[5];
  const float* Wk = (const float*)d_in[6];
  const float* bk = (const float*)d_in[7];
  const float* Wv = (const float*)d_in[8];
  const float* bv = (const float*)d_in[9];
  const float* Wb = (const float*)d_in[10];
  const float* bb = (const float*)d_in[11];
  const float* Wo = (const float*)d_in[12];
  const float* bo = (const float*)d_in[13];
  float* out = (float*)d_out;

  // workspace: qh/kh/vh bf16 (8.39 MB each) + attn fp32 (16.8 MB) = 41.9 MB
  short* qh = (short*)d_ws;
  short* kh = qh + (size_t)4194304;
  short* vh = kh + (size_t)4194304;
  float* attn_ws = (float*)(vh + (size_t)4194304);

  dim3 g(128, 8), blk(256);
  gemm_xwT<0><<<g, blk, 0, stream>>>(q, Wq, bq, nullptr, qh);
  gemm_xwT<1><<<g, blk, 0, stream>>>(k, Wk, bk, nullptr, kh);
  gemm_xwT<2><<<g, blk, 0, stream>>>(v, Wv, bv, nullptr, vh);
  flash_attn<<<512, 512, 0, stream>>>(qh, kh, vh, attn_bias, Wb, bb, attn_ws);
  gemm_xwT<3><<<g, blk, 0, stream>>>(attn_ws, Wo, bo, out, nullptr);
}

// Round 2
// 1041.412 us; speedup vs baseline: 1.1673x; 1.1673x over previous
//
#include <hip/hip_runtime.h>
#include <cstdint>
#include <cstddef>

#define BB 4
#define SS 2048
#define HIDD 512
#define HH 8
#define DHH 64
#define DBB 8

typedef __attribute__((ext_vector_type(4))) float f32x4;
typedef __attribute__((ext_vector_type(8))) short s16x8;

__device__ __forceinline__ short f2bf(float x) {
  unsigned u = __builtin_bit_cast(unsigned, x);
  u += 0x7FFFu + ((u >> 16) & 1u);
  return (short)(u >> 16);
}
__device__ __forceinline__ float bf2f(short s) {
  unsigned u = ((unsigned)(unsigned short)s) << 16;
  return __builtin_bit_cast(float, u);
}

// fp32 -> bf16, 8 elems/thread, vectorized
__global__ __launch_bounds__(256) void cvt_f32_bf16(const float* __restrict__ src,
                                                    short* __restrict__ dst, int n8) {
  int i = blockIdx.x * 256 + threadIdx.x;
  if (i < n8) {
    f32x4 a = *(const f32x4*)(src + (size_t)i * 8);
    f32x4 b = *(const f32x4*)(src + (size_t)i * 8 + 4);
    s16x8 o;
#pragma unroll
    for (int j = 0; j < 4; j++) { o[j] = f2bf(a[j]); o[4 + j] = f2bf(b[j]); }
    *(s16x8*)(dst + (size_t)i * 8) = o;
  }
}

// convert the 4 weight matrices (512x512 fp32 each) to bf16 in one launch
__global__ __launch_bounds__(256) void cvt_w4(const float* __restrict__ w0, const float* __restrict__ w1,
                                              const float* __restrict__ w2, const float* __restrict__ w3,
                                              short* __restrict__ dst) {
  const float* s = (blockIdx.y == 0) ? w0 : (blockIdx.y == 1) ? w1 : (blockIdx.y == 2) ? w2 : w3;
  short* d = dst + (size_t)blockIdx.y * 262144;
  int i = blockIdx.x * 256 + threadIdx.x;  // 32768 chunks of 8
  f32x4 a = *(const f32x4*)(s + (size_t)i * 8);
  f32x4 b = *(const f32x4*)(s + (size_t)i * 8 + 4);
  s16x8 o;
#pragma unroll
  for (int j = 0; j < 4; j++) { o[j] = f2bf(a[j]); o[4 + j] = f2bf(b[j]); }
  *(s16x8*)(d + (size_t)i * 8) = o;
}

// C[m][n] = sum_k A[m][k]*W[n][k] + bias[n].  A: [8192,512] bf16, W: [512,512] bf16.
// LDS-free, barrier-free: operands are L2-resident (A slab 128KB/block, W 512KB);
// MFMA fragments read directly from global. 128x128 tile, 4 waves (2x2), 4x4 frags/wave.
// MODE 0: out bf16 qh [B,H,S,D], *0.125 folded. MODE 1: kh. MODE 2: vh [B,H,D,S]. MODE 3: fp32.
template <int MODE>
__global__ __launch_bounds__(256) void gemm_bf16(const short* __restrict__ A,
                                                 const short* __restrict__ W,
                                                 const float* __restrict__ bias,
                                                 float* __restrict__ outF,
                                                 short* __restrict__ outB) {
  const int tid = threadIdx.x;
  const int wave = tid >> 6, lane = tid & 63;
  const int quad = lane >> 4, m16 = lane & 15;
  // XCD-aware remap: 256 blocks; xcd = wg&7 owns 8 contiguous m-tiles across all 4 n-tiles
  // so its A slabs (8x128KB=1MB) + W (512KB) stay resident in its private L2.
  const int wg = (int)blockIdx.x;
  const int j6 = wg & 63;
  const int mt = ((j6 & 7) << 3) | (j6 >> 3);  // m-tile 0..63
  const int nt = wg >> 6;                      // n-tile 0..3
  const int m0 = mt << 7, n0 = nt << 7;
  const int wm = (wave & 1) << 6, wn = (wave >> 1) << 6;

  f32x4 acc[4][4];
#pragma unroll
  for (int i = 0; i < 4; i++)
#pragma unroll
    for (int j = 0; j < 4; j++) acc[i][j] = (f32x4){0.f, 0.f, 0.f, 0.f};

  const short* Ab = A + (size_t)(m0 + wm + m16) * HIDD + quad * 8;
  const short* Wp = W + (size_t)(n0 + wn + m16) * HIDD + quad * 8;

  for (int k0 = 0; k0 < HIDD; k0 += 32) {
    s16x8 af[4], bfr[4];
#pragma unroll
    for (int i = 0; i < 4; i++) {
      af[i] = *(const s16x8*)(Ab + (size_t)(i * 16) * HIDD + k0);
      bfr[i] = *(const s16x8*)(Wp + (size_t)(i * 16) * HIDD + k0);
    }
#pragma unroll
    for (int i = 0; i < 4; i++)
#pragma unroll
      for (int j = 0; j < 4; j++)
        acc[i][j] = __builtin_amdgcn_mfma_f32_16x16x32_bf16(af[i], bfr[j], acc[i][j], 0, 0, 0);
  }

#pragma unroll
  for (int i = 0; i < 4; i++)
#pragma unroll
    for (int j = 0; j < 4; j++)
#pragma unroll
      for (int r = 0; r < 4; r++) {
        int m = m0 + wm + i * 16 + quad * 4 + r;  // C row = quad*4+reg (verified layout)
        int n = n0 + wn + j * 16 + m16;           // C col = lane&15
        float val = acc[i][j][r] + bias[n];
        if (MODE == 0) {
          int b_ = m >> 11, s = m & 2047, h = n >> 6, d = n & 63;
          outB[((size_t)(b_ * HH + h) * SS + s) * DHH + d] = f2bf(val * 0.125f);
        } else if (MODE == 1) {
          int b_ = m >> 11, s = m & 2047, h = n >> 6, d = n & 63;
          outB[((size_t)(b_ * HH + h) * SS + s) * DHH + d] = f2bf(val);
        } else if (MODE == 2) {
          int b_ = m >> 11, s = m & 2047, h = n >> 6, d = n & 63;
          outB[((size_t)(b_ * HH + h) * DHH + d) * SS + s] = f2bf(val);
        } else {
          outF[(size_t)m * HIDD + n] = val;
        }
      }
}

// Flash attention, bias fused. One block = (b, 16 q rows, ALL 8 heads); wave w = head w.
// K/V fragments direct from global (L2-resident). Bias register-prefetched one tile ahead.
// Single barrier per iteration via double-buffered projected-bias tile bp[2].
// launch_bounds(512,4): 128-VGPR cap — round 1's (512,8)=64 cap caused catastrophic
// scratch spill (VGPR_Count 32, WRITE_SIZE 500MB).
// Output written as bf16 so the final projection GEMM consumes it directly.
__global__ __launch_bounds__(512, 4) void flash_attn(const short* __restrict__ qh,
                                                     const short* __restrict__ kh,
                                                     const short* __restrict__ vh,
                                                     const float* __restrict__ attn_bias,
                                                     const float* __restrict__ Wb,
                                                     const float* __restrict__ bb,
                                                     short* __restrict__ attn_out) {
  __shared__ short bp[2][HH][16][34];  // projected bias, bf16, double-buffered
  __shared__ short pbuf[HH][16][40];   // per-wave P tile, A-layout staging

  const int tid = threadIdx.x;
  const int wave = tid >> 6, lane = tid & 63;
  const int quad = lane >> 4, m16 = lane & 15;
  // XCD-bijective remap (512 wg = 8 XCD * 64)
  const int wg = (int)blockIdx.x;
  const int lb = ((wg & 7) << 6) | (wg >> 3);
  const int b = lb >> 7;
  const int q0 = (lb & 127) << 4;
  const int h = wave;

  const size_t qoff = ((size_t)((b * HH + h) * SS) + q0 + m16) * DHH;
  s16x8 qf0 = *(const s16x8*)(qh + qoff + quad * 8);
  s16x8 qf1 = *(const s16x8*)(qh + qoff + 32 + quad * 8);

  const short* kbase = kh + ((size_t)(b * HH + h) * SS + m16) * DHH + quad * 8;
  const short* vbase = vh + ((size_t)((b * HH + h) * DHH) + m16) * SS + quad * 8;

  const int ql = tid >> 5, kl = tid & 31;
  const float* bptr = attn_bias + ((size_t)(b * SS + q0 + ql) * SS + kl) * DBB;

  f32x4 oacc[4];
#pragma unroll
  for (int dt = 0; dt < 4; dt++) oacc[dt] = (f32x4){0.f, 0.f, 0.f, 0.f};
  float m_r[4], l_r[4];
#pragma unroll
  for (int r = 0; r < 4; r++) { m_r[r] = -3.0e38f; l_r[r] = 0.f; }

  // prologue: project bias tile 0 into bp[0]
  {
    f32x4 c0 = *(const f32x4*)(bptr);
    f32x4 c1 = *(const f32x4*)(bptr + 4);
#pragma unroll
    for (int h2 = 0; h2 < 8; h2++) {
      float a2 = bb[h2];
#pragma unroll
      for (int d = 0; d < 4; d++) {
        a2 += c0[d] * Wb[h2 * 8 + d];
        a2 += c1[d] * Wb[h2 * 8 + 4 + d];
      }
      bp[0][h2][ql][kl] = f2bf(a2);
    }
  }
  __syncthreads();

  for (int it = 0; it < 64; ++it) {
    const int k0 = it << 5;
    const int cur = it & 1;

    // prefetch next bias tile (the only HBM stream) — consumed at iter end
    f32x4 n0, n1;
    if (it < 63) {
      const float* np = bptr + (size_t)(k0 + 32) * DBB;
      n0 = *(const f32x4*)(np);
      n1 = *(const f32x4*)(np + 4);
    }

    // ---- QK^T: 16q x 32k, K fragments direct from global ----
    f32x4 sc[2];
#pragma unroll
    for (int nt2 = 0; nt2 < 2; nt2++) {
      const short* kp = kbase + (size_t)(k0 + nt2 * 16) * DHH;
      s16x8 kf0 = *(const s16x8*)(kp);
      s16x8 kf1 = *(const s16x8*)(kp + 32);
      f32x4 z = (f32x4){0.f, 0.f, 0.f, 0.f};
      z = __builtin_amdgcn_mfma_f32_16x16x32_bf16(qf0, kf0, z, 0, 0, 0);
      z = __builtin_amdgcn_mfma_f32_16x16x32_bf16(qf1, kf1, z, 0, 0, 0);
      sc[nt2] = z;
    }

    // ---- online softmax (C layout: row = quad*4+r, col = m16) ----
#pragma unroll
    for (int r = 0; r < 4; r++) {
      int row = quad * 4 + r;
      float s0 = sc[0][r] + bf2f(bp[cur][h][row][m16]);
      float s1 = sc[1][r] + bf2f(bp[cur][h][row][16 + m16]);
      float v = fmaxf(s0, s1);
      v = fmaxf(v, __shfl_xor(v, 1, 16));
      v = fmaxf(v, __shfl_xor(v, 2, 16));
      v = fmaxf(v, __shfl_xor(v, 4, 16));
      v = fmaxf(v, __shfl_xor(v, 8, 16));
      float nm = fmaxf(m_r[r], v);
      float al = __expf(m_r[r] - nm);
      m_r[r] = nm;
      float p0 = __expf(s0 - nm);
      float p1 = __expf(s1 - nm);
      float rs = p0 + p1;
      rs += __shfl_xor(rs, 1, 16);
      rs += __shfl_xor(rs, 2, 16);
      rs += __shfl_xor(rs, 4, 16);
      rs += __shfl_xor(rs, 8, 16);
      l_r[r] = l_r[r] * al + rs;
#pragma unroll
      for (int dt = 0; dt < 4; dt++) oacc[dt][r] *= al;
      pbuf[wave][row][m16] = f2bf(p0);
      pbuf[wave][row][16 + m16] = f2bf(p1);
    }

    // ---- PV: O += P(16x32) @ V(32x64), V fragments direct from global ----
    s16x8 pf = *(const s16x8*)(&pbuf[wave][m16][quad * 8]);
#pragma unroll
    for (int dt = 0; dt < 4; dt++) {
      const short* vp = vbase + (size_t)(dt * 16) * SS + k0;
      s16x8 vf = *(const s16x8*)(vp);
      oacc[dt] = __builtin_amdgcn_mfma_f32_16x16x32_bf16(pf, vf, oacc[dt], 0, 0, 0);
    }

    // ---- project prefetched bias tile it+1 into bp[cur^1] ----
    if (it < 63) {
#pragma unroll
      for (int h2 = 0; h2 < 8; h2++) {
        float a2 = bb[h2];
#pragma unroll
        for (int d = 0; d < 4; d++) {
          a2 += n0[d] * Wb[h2 * 8 + d];
          a2 += n1[d] * Wb[h2 * 8 + 4 + d];
        }
        bp[cur ^ 1][h2][ql][kl] = f2bf(a2);
      }
    }
    __syncthreads();
  }

  // epilogue: attn_out bf16 [b, s, h*64+d]
#pragma unroll
  for (int dt = 0; dt < 4; dt++)
#pragma unroll
    for (int r = 0; r < 4; r++) {
      float val = oacc[dt][r] / l_r[r];
      attn_out[(size_t)(b * SS + q0 + quad * 4 + r) * HIDD + h * 64 + dt * 16 + m16] = f2bf(val);
    }
}

extern "C" void kernel_launch(void* const* d_in, const int* in_sizes, int n_in,
                              void* d_out, int out_size, void* d_ws, size_t ws_size,
                              hipStream_t stream) {
  const float* q = (const float*)d_in[0];
  const float* k = (const float*)d_in[1];
  const float* v = (const float*)d_in[2];
  const float* attn_bias = (const float*)d_in[3];
  const float* Wq = (const float*)d_in[4];
  const float* bq = (const float*)d_in[5];
  const float* Wk = (const float*)d_in[6];
  const float* bk = (const float*)d_in[7];
  const float* Wv = (const float*)d_in[8];
  const float* bv = (const float*)d_in[9];
  const float* Wb = (const float*)d_in[10];
  const float* bb = (const float*)d_in[11];
  const float* Wo = (const float*)d_in[12];
  const float* bo = (const float*)d_in[13];
  float* out = (float*)d_out;

  // workspace (shorts): qh, kh, vh (4.19M each) | S: shared staging slot
  // (converted input for each projection, then bf16 attn) | W4: 4 bf16 weights.
  // Total 17,825,792 shorts = 35.7 MB.
  short* qh = (short*)d_ws;
  short* kh = qh + (size_t)4194304;
  short* vh = kh + (size_t)4194304;
  short* S = vh + (size_t)4194304;
  short* W4 = S + (size_t)4194304;

  cvt_w4<<<dim3(128, 4), 256, 0, stream>>>(Wq, Wk, Wv, Wo, W4);
  cvt_f32_bf16<<<2048, 256, 0, stream>>>(q, S, 524288);
  gemm_bf16<0><<<256, 256, 0, stream>>>(S, W4, bq, nullptr, qh);
  cvt_f32_bf16<<<2048, 256, 0, stream>>>(k, S, 524288);
  gemm_bf16<1><<<256, 256, 0, stream>>>(S, W4 + 262144, bk, nullptr, kh);
  cvt_f32_bf16<<<2048, 256, 0, stream>>>(v, S, 524288);
  gemm_bf16<2><<<256, 256, 0, stream>>>(S, W4 + 524288, bv, nullptr, vh);
  flash_attn<<<512, 512, 0, stream>>>(qh, kh, vh, attn_bias, Wb, bb, S);
  gemm_bf16<3><<<256, 256, 0, stream>>>(S, W4 + 786432, bo, out, nullptr);
}